// Round 3
// baseline (1426.390 us; speedup 1.0000x reference)
//
#include <hip/hip_runtime.h>

typedef unsigned short u16;
typedef unsigned int u32;
typedef __attribute__((ext_vector_type(8))) short short8;
typedef __attribute__((ext_vector_type(4))) float floatx4;

#define SCALE_Q 0.17677669529663687f  // 32^-0.5

__device__ __forceinline__ u16 f2bf(float f) {
  u32 u = __float_as_uint(f);
  u = (u + 0x7fffu + ((u >> 16) & 1u)) >> 16;
  return (u16)u;
}

__device__ __forceinline__ void gload_lds16(const void* g, void* l) {
  __builtin_amdgcn_global_load_lds(
      (const __attribute__((address_space(1))) u32*)g,
      (__attribute__((address_space(3))) u32*)l, 16, 0, 0);
}

__device__ __forceinline__ floatx4 mfma16(short8 a, short8 b, floatx4 c) {
  return __builtin_amdgcn_mfma_f32_16x16x32_bf16(a, b, c, 0, 0, 0);
}

// ---------------- prep: cast weights to bf16 ----------------
__global__ void cast_w_kernel(const float* __restrict__ qkv_w,
                              const float* __restrict__ proj_w,
                              u16* __restrict__ wb1, u16* __restrict__ wb2) {
  int idx = blockIdx.x * 256 + threadIdx.x;   // grid covers 442368 exactly
  wb1[idx] = f2bf(qkv_w[idx]);
  if (idx < 147456) wb2[idx] = f2bf(proj_w[idx]);
}

// ---------------- prep: cast x to bf16 (8 elems/thread) ----------------
__global__ __launch_bounds__(256) void cast_x_kernel(const float* __restrict__ x,
                                                     u16* __restrict__ xb) {
  const size_t i = ((size_t)blockIdx.x * 256 + threadIdx.x) * 8;  // grid covers 77070336
  const float4 f0 = *(const float4*)(x + i);
  const float4 f1 = *(const float4*)(x + i + 4);
  uint4 pk;
  pk.x = (u32)f2bf(f0.x) | ((u32)f2bf(f0.y) << 16);
  pk.y = (u32)f2bf(f0.z) | ((u32)f2bf(f0.w) << 16);
  pk.z = (u32)f2bf(f1.x) | ((u32)f2bf(f1.y) << 16);
  pk.w = (u32)f2bf(f1.z) | ((u32)f2bf(f1.w) << 16);
  *(uint4*)(xb + i) = pk;
}

// ---- prep: combined bias+mask table, transposed+padded: comb[w][h][key(64)][query(64)] ----
__global__ void comb_kernel(const float* __restrict__ bias_table,
                            const float* __restrict__ mask,
                            float* __restrict__ comb) {
  int wh = blockIdx.x;          // 768 = 64 windows * 12 heads
  int w = wh / 12, h = wh - w * 12;
  float* dst = comb + (size_t)wh * 4096;
  for (int e = threadIdx.x; e < 4096; e += 256) {
    int q = e >> 6, p = e & 63;   // q = key token, p = query token
    float v;
    if (q >= 49) v = -1e30f;          // padded key columns -> softmax zero
    else if (p >= 49) v = 0.0f;       // padded query rows: keep finite
    else {
      int pi = p / 7, pj = p - pi * 7;
      int qi = q / 7, qj = q - qi * 7;
      int ridx = (pi - qi + 6) * 13 + (pj - qj + 6);
      v = bias_table[ridx * 12 + h] + mask[(size_t)w * 2401 + p * 49 + q];
    }
    dst[e] = v;                       // e = key*64 + query (for float4 reads over reg axis)
  }
}

// ---------------- QKV GEMM: (200704x384 bf16) @ (1152x384 bf16)^T + b -> bf16 ----------------
// R0's proven stage->sync->compute->sync structure (16KB LDS, single buffer) +
// XOR-swizzled k-chunks (same coalesced global pattern, 0 LDS bank conflicts) +
// head-major output [which(3)][b(4096)][h(12)][tok(49)][d(32)] for coalesced attention.
__global__ __launch_bounds__(256) void qkv_gemm(const u16* __restrict__ A,
                                                const u16* __restrict__ B,
                                                const float* __restrict__ bias,
                                                u16* __restrict__ C) {
  __shared__ u16 As[4096];  // 8KB: [m(128)][kchunk(4, XOR-permuted)][8]
  __shared__ u16 Bs[4096];
  const int tid = threadIdx.x;
  const int lane = tid & 63;
  const int wave = tid >> 6;
  const int l15 = lane & 15;
  const int quad = lane >> 4;
  const int wr = wave >> 1, wc = wave & 1;
  // swizzle: grid 14112 = 8 xcd * 196 grp * 9 tn
  const u32 bid = blockIdx.x;
  const u32 xcd = bid & 7;
  const u32 slot = bid >> 3;        // 0..1763
  const u32 grp = slot / 9;
  const u32 tn = slot - grp * 9;
  const u32 tm = xcd * 196 + grp;   // 0..1567

  // staging map: 16B slot c holds A[m=c>>2][k0 + kp*8 ..) with kp = (c&3)^((m>>1)&3)
  const int c0 = tid, c1 = tid + 256;
  const int m0 = c0 >> 2, kp0 = (c0 & 3) ^ ((m0 >> 1) & 3);
  const int m1 = c1 >> 2, kp1 = (c1 & 3) ^ ((m1 >> 1) & 3);
  const u16* Ab0 = A + (size_t)(tm * 128 + m0) * 384 + kp0 * 8;
  const u16* Ab1 = A + (size_t)(tm * 128 + m1) * 384 + kp1 * 8;
  const u16* Bb0 = B + (size_t)(tn * 128 + m0) * 384 + kp0 * 8;
  const u16* Bb1 = B + (size_t)(tn * 128 + m1) * 384 + kp1 * 8;
  const int ld0 = c0 * 8, ld1 = c1 * 8;

  floatx4 acc[4][4];
#pragma unroll
  for (int i = 0; i < 4; ++i)
#pragma unroll
    for (int j = 0; j < 4; ++j) acc[i][j] = (floatx4){0.f, 0.f, 0.f, 0.f};

  // read-side XOR: row = wr*64+i*16+l15 -> ((row>>1)&3) == ((l15>>1)&3)
  const int xq = quad ^ ((l15 >> 1) & 3);
  const int abase = (wr * 64 + l15) * 32 + xq * 8;
  const int bbase = (wc * 64 + l15) * 32 + xq * 8;
  for (int kb = 0; kb < 12; ++kb) {
    const int k0 = kb * 32;
    gload_lds16(Ab0 + k0, &As[ld0]);
    gload_lds16(Ab1 + k0, &As[ld1]);
    gload_lds16(Bb0 + k0, &Bs[ld0]);
    gload_lds16(Bb1 + k0, &Bs[ld1]);
    __syncthreads();
    short8 af[4], bfr[4];
#pragma unroll
    for (int i = 0; i < 4; ++i)
      af[i] = *(const short8*)(&As[abase + i * 512]);
#pragma unroll
    for (int i = 0; i < 4; ++i)
      bfr[i] = *(const short8*)(&Bs[bbase + i * 512]);
#pragma unroll
    for (int mi = 0; mi < 4; ++mi)
#pragma unroll
      for (int ni = 0; ni < 4; ++ni)
        acc[mi][ni] = mfma16(af[mi], bfr[ni], acc[mi][ni]);
    __syncthreads();
  }

  // epilogue: +bias, fold SCALE into q; head-major output layout
#pragma unroll
  for (int ni = 0; ni < 4; ++ni) {
    const int gbase = (int)tn * 128 + wc * 64 + ni * 16;   // 16-aligned, no head crossing
    const int which = gbase / 384;
    const int rem = gbase - which * 384;
    const int h = rem >> 5;
    const int db = rem & 31;
    const float bb = bias[gbase + l15];
    const float scale = (which == 0) ? SCALE_Q : 1.0f;
    u16* hp = C + ((size_t)which * 49152 + h) * 1568 + db + l15;
#pragma unroll
    for (int mi = 0; mi < 4; ++mi) {
      const int grow0 = (int)tm * 128 + wr * 64 + mi * 16 + quad * 4;
#pragma unroll
      for (int r = 0; r < 4; ++r) {
        const int grow = grow0 + r;
        const int b = grow / 49;
        const int tok = grow - b * 49;
        hp[(size_t)b * 18816 + tok * 32] = f2bf((acc[mi][ni][r] + bb) * scale);
      }
    }
  }
}

// ---------------- fused attention+proj: one block (4 waves) per window ----------------
// Wave wv runs heads {wv, wv+4, wv+8} with per-wave Ps/Vt LDS buffers; attention output
// goes to shared aoS[64][392] bf16 (pad 8 per row -> balanced LDS banks). Then all waves
// do the 64x384x384 proj GEMM: A from aoS, B=proj_w bf16 from global (L2-resident).
// Grid order: w = bid>>6, so concurrent blocks share the same comb slice in L2.
// LDS: aoS 50176 + Ps 4x9216 + Vt 4x4608 = 105472 B -> 1 block/CU.
__global__ __launch_bounds__(256, 1) void attn_proj(const u16* __restrict__ qkv,
                                                    const float* __restrict__ comb,
                                                    const u16* __restrict__ pw,
                                                    const float* __restrict__ pb,
                                                    float* __restrict__ out) {
  __shared__ uint4 smem[6592];                              // 105472 B
  u16* aoS = (u16*)smem;                                    // [64][392]
  const int tid = threadIdx.x;
  const int lane = tid & 63;
  const int wv = tid >> 6;
  const int l15 = lane & 15, quad = lane >> 4;
  u16* Ps = (u16*)((char*)smem + 50176 + wv * 9216);        // [64][72]
  u16* Vt = (u16*)((char*)smem + 87040 + wv * 4608);        // [32][72]

  const int bid = blockIdx.x;
  const int w = bid >> 6;
  const int b = (bid & 63) * 64 + w;                        // b & 63 == w

  // zero Vt once (pad tokens 49..63 must be finite; exact-0 P kills their contribution)
  {
    uint4* v4 = (uint4*)Vt;
    const uint4 zz = make_uint4(0u, 0u, 0u, 0u);
    for (int i = lane; i < 288; i += 64) v4[i] = zz;
  }

  const floatx4 z4 = (floatx4){0.f, 0.f, 0.f, 0.f};
  const short8 z8 = {0, 0, 0, 0, 0, 0, 0, 0};

  for (int hi = 0; hi < 3; ++hi) {
    const int h = wv + hi * 4;
    const size_t hoff = (size_t)(b * 12 + h) * 1568;
    const u16* qb = qkv + hoff;
    const u16* kbp = qkv + (size_t)49152 * 1568 + hoff;
    const u16* vb = qkv + (size_t)98304 * 1568 + hoff;

    // Q/K frags direct from global (1KB contiguous per 64-lane frag load)
    short8 aq[4], bk[4];
#pragma unroll
    for (int i = 0; i < 3; ++i) {
      aq[i] = *(const short8*)(qb + (i * 16 + l15) * 32 + quad * 8);
      bk[i] = *(const short8*)(kbp + (i * 16 + l15) * 32 + quad * 8);
    }
    aq[3] = (l15 == 0) ? *(const short8*)(qb + 48 * 32 + quad * 8) : z8;
    bk[3] = (l15 == 0) ? *(const short8*)(kbp + 48 * 32 + quad * 8) : z8;

    // V load (contiguous) + transpose into Vt[d][t]
    for (int s0 = lane; s0 < 196; s0 += 64) {
      const int t = s0 >> 2, part = s0 & 3;
      const uint4 dv = *(const uint4*)(vb + t * 32 + part * 8);
      const int d0 = part * 8;
      const u32 vv[4] = {dv.x, dv.y, dv.z, dv.w};
#pragma unroll
      for (int e = 0; e < 4; ++e) {
        Vt[(d0 + 2 * e) * 72 + t] = (u16)(vv[e] & 0xffffu);
        Vt[(d0 + 2 * e + 1) * 72 + t] = (u16)(vv[e] >> 16);
      }
    }

    // S = Q K^T: col=key=ni*16+l15, row=query=mi*16+quad*4+r
    floatx4 s[4][4];
    __builtin_amdgcn_s_setprio(1);
#pragma unroll
    for (int mi = 0; mi < 4; ++mi)
#pragma unroll
      for (int ni = 0; ni < 4; ++ni) s[mi][ni] = mfma16(aq[mi], bk[ni], z4);
    __builtin_amdgcn_s_setprio(0);

    // combined bias+mask
    const float* cb = comb + (size_t)(w * 12 + h) * 4096;
#pragma unroll
    for (int ni = 0; ni < 4; ++ni)
#pragma unroll
      for (int mi = 0; mi < 4; ++mi) {
        const float4 cv = *(const float4*)(cb + (ni * 16 + l15) * 64 + mi * 16 + quad * 4);
        s[mi][ni][0] += cv.x;
        s[mi][ni][1] += cv.y;
        s[mi][ni][2] += cv.z;
        s[mi][ni][3] += cv.w;
      }

    // softmax: 16-lane shuffle reduce across {ni, l15}
    floatx4 mx[4], sm[4];
#pragma unroll
    for (int mi = 0; mi < 4; ++mi)
#pragma unroll
      for (int r = 0; r < 4; ++r)
        mx[mi][r] = fmaxf(fmaxf(s[mi][0][r], s[mi][1][r]), fmaxf(s[mi][2][r], s[mi][3][r]));
#pragma unroll
    for (int d = 1; d < 16; d <<= 1)
#pragma unroll
      for (int mi = 0; mi < 4; ++mi)
#pragma unroll
        for (int r = 0; r < 4; ++r)
          mx[mi][r] = fmaxf(mx[mi][r], __shfl_xor(mx[mi][r], d));
#pragma unroll
    for (int mi = 0; mi < 4; ++mi)
#pragma unroll
      for (int r = 0; r < 4; ++r) {
        float a = 0.f;
#pragma unroll
        for (int ni = 0; ni < 4; ++ni) {
          const float e = __expf(s[mi][ni][r] - mx[mi][r]);
          s[mi][ni][r] = e;
          a += e;
        }
        sm[mi][r] = a;
      }
#pragma unroll
    for (int d = 1; d < 16; d <<= 1)
#pragma unroll
      for (int mi = 0; mi < 4; ++mi)
#pragma unroll
        for (int r = 0; r < 4; ++r)
          sm[mi][r] += __shfl_xor(sm[mi][r], d);

    // P -> Ps (bf16, A-operand layout round trip)
#pragma unroll
    for (int mi = 0; mi < 4; ++mi)
#pragma unroll
      for (int r = 0; r < 4; ++r) {
        const float rinv = 1.0f / sm[mi][r];
        const int row = mi * 16 + quad * 4 + r;
#pragma unroll
        for (int ni = 0; ni < 4; ++ni)
          Ps[row * 72 + ni * 16 + l15] = f2bf(s[mi][ni][r] * rinv);
      }
    __syncthreads();  // uniform across waves (3 iters each); orders Ps/Vt writes

    // O = P V
    floatx4 o[4][2];
#pragma unroll
    for (int mi = 0; mi < 4; ++mi)
#pragma unroll
      for (int ni = 0; ni < 2; ++ni) o[mi][ni] = z4;
#pragma unroll
    for (int kk = 0; kk < 2; ++kk) {
      short8 ap[4], bv[2];
#pragma unroll
      for (int mi = 0; mi < 4; ++mi)
        ap[mi] = *(const short8*)(Ps + (mi * 16 + l15) * 72 + kk * 32 + quad * 8);
#pragma unroll
      for (int ni = 0; ni < 2; ++ni)
        bv[ni] = *(const short8*)(Vt + (ni * 16 + l15) * 72 + kk * 32 + quad * 8);
      __builtin_amdgcn_s_setprio(1);
#pragma unroll
      for (int mi = 0; mi < 4; ++mi)
#pragma unroll
        for (int ni = 0; ni < 2; ++ni) o[mi][ni] = mfma16(ap[mi], bv[ni], o[mi][ni]);
      __builtin_amdgcn_s_setprio(0);
    }
    // attention output -> aoS (all 64 rows; pad rows are finite and never stored)
#pragma unroll
    for (int mi = 0; mi < 4; ++mi)
#pragma unroll
      for (int r = 0; r < 4; ++r) {
        const int row = mi * 16 + quad * 4 + r;
#pragma unroll
        for (int ni = 0; ni < 2; ++ni)
          aoS[row * 392 + h * 32 + ni * 16 + l15] = f2bf(o[mi][ni][r]);
      }
  }

  __syncthreads();  // aoS complete across all waves

  // ---- proj GEMM: (64x384 from aoS) @ (384x384 pw)^T, wave wv owns cols wv*96..+96 ----
  floatx4 pacc[4][6];
#pragma unroll
  for (int mi = 0; mi < 4; ++mi)
#pragma unroll
    for (int nf = 0; nf < 6; ++nf) pacc[mi][nf] = z4;

  const u16* pwb = pw + (size_t)(wv * 96 + l15) * 384 + quad * 8;
#pragma unroll
  for (int kb = 0; kb < 12; ++kb) {
    short8 paf[4], pbf[6];
#pragma unroll
    for (int mi = 0; mi < 4; ++mi)
      paf[mi] = *(const short8*)(aoS + (mi * 16 + l15) * 392 + kb * 32 + quad * 8);
#pragma unroll
    for (int nf = 0; nf < 6; ++nf)
      pbf[nf] = *(const short8*)(pwb + nf * 6144 + kb * 32);
    __builtin_amdgcn_s_setprio(1);
#pragma unroll
    for (int mi = 0; mi < 4; ++mi)
#pragma unroll
      for (int nf = 0; nf < 6; ++nf)
        pacc[mi][nf] = mfma16(paf[mi], pbf[nf], pacc[mi][nf]);
    __builtin_amdgcn_s_setprio(0);
  }

#pragma unroll
  for (int nf = 0; nf < 6; ++nf) {
    const int col = wv * 96 + nf * 16 + l15;
    const float bb = pb[col];
#pragma unroll
    for (int mi = 0; mi < 4; ++mi)
#pragma unroll
      for (int r = 0; r < 4; ++r) {
        const int row = mi * 16 + quad * 4 + r;
        if (row < 49)
          out[((size_t)b * 49 + row) * 384 + col] = pacc[mi][nf][r] + bb;
      }
  }
}

// ---------------- launcher ----------------
extern "C" void kernel_launch(void* const* d_in, const int* in_sizes, int n_in,
                              void* d_out, int out_size, void* d_ws, size_t ws_size,
                              hipStream_t stream) {
  const float* x = (const float*)d_in[0];
  const float* mask = (const float*)d_in[1];
  const float* qkv_w = (const float*)d_in[2];
  const float* qkv_b = (const float*)d_in[3];
  const float* proj_w = (const float*)d_in[4];
  const float* proj_b = (const float*)d_in[5];
  const float* bias_table = (const float*)d_in[6];
  float* out = (float*)d_out;
  char* ws = (char*)d_ws;

  u16* wb1 = (u16*)(ws);                        // 442368 bf16 = 884736 B
  u16* wb2 = (u16*)(ws + 884736);               // 147456 bf16 = 294912 B
  float* comb = (float*)(ws + 1179648);         // 768*4096 f32 = 12582912 B
  u16* qkvb = (u16*)(ws + 13762560);            // 200704*1152 bf16 = 462422016 B (head-major)
  u16* xb = (u16*)(ws + 476184576);             // 200704*384 bf16 = 154140672 B
  // total ws use: 630325248 B

  hipLaunchKernelGGL(cast_w_kernel, dim3(1728), dim3(256), 0, stream, qkv_w, proj_w, wb1, wb2);
  hipLaunchKernelGGL(cast_x_kernel, dim3(37632), dim3(256), 0, stream, x, xb);
  hipLaunchKernelGGL(comb_kernel, dim3(768), dim3(256), 0, stream, bias_table, mask, comb);
  hipLaunchKernelGGL(qkv_gemm, dim3(14112), dim3(256), 0, stream, xb, wb1, qkv_b, qkvb);
  hipLaunchKernelGGL(attn_proj, dim3(4096), dim3(256), 0, stream, qkvb, comb, wb2, proj_b, out);
}

// Round 4
// 1193.911 us; speedup vs baseline: 1.1947x; 1.1947x over previous
//
#include <hip/hip_runtime.h>

typedef unsigned short u16;
typedef unsigned int u32;
typedef __attribute__((ext_vector_type(8))) short short8;
typedef __attribute__((ext_vector_type(4))) float floatx4;
typedef __attribute__((ext_vector_type(4))) unsigned int u32x4;

#define SCALE_Q 0.17677669529663687f  // 32^-0.5

__device__ __forceinline__ u16 f2bf(float f) {
  u32 u = __float_as_uint(f);
  u = (u + 0x7fffu + ((u >> 16) & 1u)) >> 16;
  return (u16)u;
}

__device__ __forceinline__ void gload_lds16(const void* g, void* l) {
  __builtin_amdgcn_global_load_lds(
      (const __attribute__((address_space(1))) u32*)g,
      (__attribute__((address_space(3))) u32*)l, 16, 0, 0);
}

__device__ __forceinline__ floatx4 mfma16(short8 a, short8 b, floatx4 c) {
  return __builtin_amdgcn_mfma_f32_16x16x32_bf16(a, b, c, 0, 0, 0);
}

// ---------------- prep: cast weights to bf16 ----------------
__global__ void cast_w_kernel(const float* __restrict__ qkv_w,
                              const float* __restrict__ proj_w,
                              u16* __restrict__ wb1, u16* __restrict__ wb2) {
  int idx = blockIdx.x * 256 + threadIdx.x;   // grid covers 442368 exactly
  wb1[idx] = f2bf(qkv_w[idx]);
  if (idx < 147456) wb2[idx] = f2bf(proj_w[idx]);
}

// ---------------- prep: cast x to bf16 (8 elems/thread) ----------------
__global__ __launch_bounds__(256) void cast_x_kernel(const float* __restrict__ x,
                                                     u16* __restrict__ xb) {
  const size_t i = ((size_t)blockIdx.x * 256 + threadIdx.x) * 8;  // grid covers 77070336
  const float4 f0 = *(const float4*)(x + i);
  const float4 f1 = *(const float4*)(x + i + 4);
  uint4 pk;
  pk.x = (u32)f2bf(f0.x) | ((u32)f2bf(f0.y) << 16);
  pk.y = (u32)f2bf(f0.z) | ((u32)f2bf(f0.w) << 16);
  pk.z = (u32)f2bf(f1.x) | ((u32)f2bf(f1.y) << 16);
  pk.w = (u32)f2bf(f1.z) | ((u32)f2bf(f1.w) << 16);
  *(uint4*)(xb + i) = pk;
}

// ---- prep: combined bias+mask table: comb[w][h][query(64)][key(64)] (QUERY-major now) ----
__global__ void comb_kernel(const float* __restrict__ bias_table,
                            const float* __restrict__ mask,
                            float* __restrict__ comb) {
  int wh = blockIdx.x;          // 768 = 64 windows * 12 heads
  int w = wh / 12, h = wh - w * 12;
  float* dst = comb + (size_t)wh * 4096;
  for (int e = threadIdx.x; e < 4096; e += 256) {
    int p = e >> 6, q = e & 63;   // p = query token, q = key token
    float v;
    if (q >= 49) v = -1e30f;          // padded key columns -> softmax zero
    else if (p >= 49) v = 0.0f;       // padded query rows: keep finite
    else {
      int pi = p / 7, pj = p - pi * 7;
      int qi = q / 7, qj = q - qi * 7;
      int ridx = (pi - qi + 6) * 13 + (pj - qj + 6);
      v = bias_table[ridx * 12 + h] + mask[(size_t)w * 2401 + p * 49 + q];
    }
    dst[e] = v;                       // e = query*64 + key (float4 reads over key/reg axis)
  }
}

// ---------------- QKV GEMM: (200704x384 bf16) @ (1152x384 bf16)^T + b -> bf16 ----------------
// R2-verbatim (measured 378us): 128x128 tile, dbuf 2-phase prefetch, XOR k-chunk swizzle
// (coalesced staging, 0 LDS bank conflicts), head-major output
// [which(3)][b(4096)][h(12)][tok(49)][d(32)] for coalesced attention reads.
__global__ __launch_bounds__(256) void qkv_gemm(const u16* __restrict__ A,
                                                const u16* __restrict__ B,
                                                const float* __restrict__ bias,
                                                u16* __restrict__ C) {
  __shared__ u16 As[2][4096];  // 8KB per buffer: [m(128)][kchunk(4, XOR-permuted)][8]
  __shared__ u16 Bs[2][4096];
  const int tid = threadIdx.x;
  const int lane = tid & 63;
  const int wave = tid >> 6;
  const int l15 = lane & 15;
  const int quad = lane >> 4;
  const int wr = wave >> 1, wc = wave & 1;
  // swizzle: grid 14112 = 8 xcd * 196 grp * 9 tn
  const u32 bid = blockIdx.x;
  const u32 xcd = bid & 7;
  const u32 slot = bid >> 3;        // 0..1763
  const u32 grp = slot / 9;
  const u32 tn = slot - grp * 9;
  const u32 tm = xcd * 196 + grp;   // 0..1567

  // staging map: 16B slot c holds A[m=c>>2][k0 + kp*8 ..) with kp = (c&3)^((m>>1)&3)
  const int c0 = tid, c1 = tid + 256;
  const int m0 = c0 >> 2, kp0 = (c0 & 3) ^ ((m0 >> 1) & 3);
  const int m1 = c1 >> 2, kp1 = (c1 & 3) ^ ((m1 >> 1) & 3);
  const u16* Ab0 = A + (size_t)(tm * 128 + m0) * 384 + kp0 * 8;
  const u16* Ab1 = A + (size_t)(tm * 128 + m1) * 384 + kp1 * 8;
  const u16* Bb0 = B + (size_t)(tn * 128 + m0) * 384 + kp0 * 8;
  const u16* Bb1 = B + (size_t)(tn * 128 + m1) * 384 + kp1 * 8;
  const int ld0 = c0 * 8, ld1 = c1 * 8;

  floatx4 acc[4][4];
#pragma unroll
  for (int i = 0; i < 4; ++i)
#pragma unroll
    for (int j = 0; j < 4; ++j) acc[i][j] = (floatx4){0.f, 0.f, 0.f, 0.f};

#define QSTAGE(buf, k0)                       \
  do {                                        \
    gload_lds16(Ab0 + (k0), &As[buf][ld0]);   \
    gload_lds16(Ab1 + (k0), &As[buf][ld1]);   \
    gload_lds16(Bb0 + (k0), &Bs[buf][ld0]);   \
    gload_lds16(Bb1 + (k0), &Bs[buf][ld1]);   \
  } while (0)

  QSTAGE(0, 0);
  __syncthreads();

  // read-side XOR: row = wr*64+i*16+l15 -> ((row>>1)&3) == ((l15>>1)&3)
  const int xq = quad ^ ((l15 >> 1) & 3);
  const int abase = (wr * 64 + l15) * 32 + xq * 8;
  const int bbase = (wc * 64 + l15) * 32 + xq * 8;
  for (int kb = 0; kb < 12; ++kb) {
    const int cur = kb & 1;
    if (kb < 11) QSTAGE(cur ^ 1, (kb + 1) * 32);   // prefetch overlaps compute below
    short8 af[4], bfr[4];
#pragma unroll
    for (int i = 0; i < 4; ++i)
      af[i] = *(const short8*)(&As[cur][abase + i * 512]);
#pragma unroll
    for (int i = 0; i < 4; ++i)
      bfr[i] = *(const short8*)(&Bs[cur][bbase + i * 512]);
#pragma unroll
    for (int mi = 0; mi < 4; ++mi)
#pragma unroll
      for (int ni = 0; ni < 4; ++ni)
        acc[mi][ni] = mfma16(af[mi], bfr[ni], acc[mi][ni]);
    if (kb < 11) __syncthreads();   // drains prefetch + guards buffer reuse
  }
#undef QSTAGE

  // epilogue: +bias, fold SCALE into q; head-major output layout
#pragma unroll
  for (int ni = 0; ni < 4; ++ni) {
    const int gbase = (int)tn * 128 + wc * 64 + ni * 16;   // 16-aligned, no head crossing
    const int which = gbase / 384;
    const int rem = gbase - which * 384;
    const int h = rem >> 5;
    const int db = rem & 31;
    const float bb = bias[gbase + l15];
    const float scale = (which == 0) ? SCALE_Q : 1.0f;
    u16* hp = C + ((size_t)which * 49152 + h) * 1568 + db + l15;
#pragma unroll
    for (int mi = 0; mi < 4; ++mi) {
      const int grow0 = (int)tm * 128 + wr * 64 + mi * 16 + quad * 4;
#pragma unroll
      for (int r = 0; r < 4; ++r) {
        const int grow = grow0 + r;
        const int b = grow / 49;
        const int tok = grow - b * 49;
        hp[(size_t)b * 18816 + tok * 32] = f2bf((acc[mi][ni][r] + bb) * scale);
      }
    }
  }
}

// ---------------- fused attention+proj: one block (4 waves) per window ----------------
// SWAPPED QK^T: St = mfma(K,Q) -> row=key, col=query. Softmax is lane-local(16) +
// 2 shfl_xor. P^T goes to the PV B-operand via an 8-shfl quad-permutation — NO Ps LDS
// buffer, no per-head __syncthreads. LDS: aoS 50176 + 4x Vt 4608 = 68608 B -> 2 blk/CU.
__global__ __launch_bounds__(256, 2) void attn_proj(const u16* __restrict__ qkv,
                                                    const float* __restrict__ comb,
                                                    const u16* __restrict__ pw,
                                                    const float* __restrict__ pb,
                                                    float* __restrict__ out) {
  __shared__ uint4 smem[4288];                              // 68608 B
  u16* aoS = (u16*)smem;                                    // [64][392]
  const int tid = threadIdx.x;
  const int lane = tid & 63;
  const int wv = tid >> 6;
  const int l15 = lane & 15, quad = lane >> 4;
  u16* Vt = (u16*)((char*)smem + 50176 + wv * 4608);        // [32][72] per wave

  const int bid = blockIdx.x;
  const int w = bid >> 6;                                   // comb slice shared in L2
  const int b = (bid & 63) * 64 + w;                        // b & 63 == w

  // zero Vt once (pad tokens 49..71 must be exactly 0)
  {
    uint4* v4 = (uint4*)Vt;
    const uint4 zz = make_uint4(0u, 0u, 0u, 0u);
    for (int i = lane; i < 288; i += 64) v4[i] = zz;
  }

  const floatx4 z4 = (floatx4){0.f, 0.f, 0.f, 0.f};
  const short8 z8 = {0, 0, 0, 0, 0, 0, 0, 0};

  for (int hi = 0; hi < 3; ++hi) {
    const int h = wv + hi * 4;
    const size_t hoff = (size_t)(b * 12 + h) * 1568;
    const u16* qb = qkv + hoff;
    const u16* kbp = qkv + (size_t)49152 * 1568 + hoff;
    const u16* vb = qkv + (size_t)98304 * 1568 + hoff;

    // Q (B-operand) / K (A-operand) frags direct from global
    short8 aq[4], bk[4];
#pragma unroll
    for (int i = 0; i < 3; ++i) {
      aq[i] = *(const short8*)(qb + (i * 16 + l15) * 32 + quad * 8);
      bk[i] = *(const short8*)(kbp + (i * 16 + l15) * 32 + quad * 8);
    }
    aq[3] = (l15 == 0) ? *(const short8*)(qb + 48 * 32 + quad * 8) : z8;
    bk[3] = (l15 == 0) ? *(const short8*)(kbp + 48 * 32 + quad * 8) : z8;

    // V load (contiguous) + transpose into Vt[d][t]
    for (int s0 = lane; s0 < 196; s0 += 64) {
      const int t = s0 >> 2, part = s0 & 3;
      const uint4 dv = *(const uint4*)(vb + t * 32 + part * 8);
      const int d0 = part * 8;
      const u32 vv[4] = {dv.x, dv.y, dv.z, dv.w};
#pragma unroll
      for (int e = 0; e < 4; ++e) {
        Vt[(d0 + 2 * e) * 72 + t] = (u16)(vv[e] & 0xffffu);
        Vt[(d0 + 2 * e + 1) * 72 + t] = (u16)(vv[e] >> 16);
      }
    }

    // St = K Q^T (swapped): row=key=mi*16+quad*4+r, col=query=ni*16+l15
    floatx4 st[4][4];
    __builtin_amdgcn_s_setprio(1);
#pragma unroll
    for (int mi = 0; mi < 4; ++mi)
#pragma unroll
      for (int ni = 0; ni < 4; ++ni) st[mi][ni] = mfma16(bk[mi], aq[ni], z4);
    __builtin_amdgcn_s_setprio(0);

    // comb[w][h][query][key]: float4 over key/reg axis
    const float* cb = comb + (size_t)(w * 12 + h) * 4096;
#pragma unroll
    for (int ni = 0; ni < 4; ++ni)
#pragma unroll
      for (int mi = 0; mi < 4; ++mi) {
        const float4 cv = *(const float4*)(cb + (ni * 16 + l15) * 64 + mi * 16 + quad * 4);
        st[mi][ni][0] += cv.x;
        st[mi][ni][1] += cv.y;
        st[mi][ni][2] += cv.z;
        st[mi][ni][3] += cv.w;
      }

    // softmax over keys: 16 lane-local + cross-quad shfl (lanes l15, l15+16, +32, +48)
    float rinv[4];
#pragma unroll
    for (int ni = 0; ni < 4; ++ni) {
      float mx = st[0][ni][0];
#pragma unroll
      for (int mi = 0; mi < 4; ++mi)
#pragma unroll
        for (int r = 0; r < 4; ++r) mx = fmaxf(mx, st[mi][ni][r]);
      mx = fmaxf(mx, __shfl_xor(mx, 16));
      mx = fmaxf(mx, __shfl_xor(mx, 32));
      float sum = 0.f;
#pragma unroll
      for (int mi = 0; mi < 4; ++mi)
#pragma unroll
        for (int r = 0; r < 4; ++r) {
          const float e = __expf(st[mi][ni][r] - mx);
          st[mi][ni][r] = e;
          sum += e;
        }
      sum += __shfl_xor(sum, 16);
      sum += __shfl_xor(sum, 32);
      rinv[ni] = 1.0f / sum;
    }

    // pack P^T to bf16 pairs: pk[mi][ni][t] = keys (mi*16+quad*4+2t, +1) for query (ni,l15)
    u32 pk[4][4][2];
#pragma unroll
    for (int mi = 0; mi < 4; ++mi)
#pragma unroll
      for (int ni = 0; ni < 4; ++ni)
#pragma unroll
        for (int t = 0; t < 2; ++t)
          pk[mi][ni][t] = (u32)f2bf(st[mi][ni][2 * t] * rinv[ni]) |
                          ((u32)f2bf(st[mi][ni][2 * t + 1] * rinv[ni]) << 16);

    // O^T = V^T P^T : M=32 dims (mb), N=64 queries (nb), K=64 keys (kk)
    floatx4 ot[2][4];
#pragma unroll
    for (int mb = 0; mb < 2; ++mb)
#pragma unroll
      for (int nb = 0; nb < 4; ++nb) ot[mb][nb] = z4;

    // b-frag reg t needs keys kk*32+quad*8+{2t,2t+1} = pk[kk*2+(quad>>1)][nb][t&1]
    // pulled from lane ((quad&1)*2 + (t>>1))*16 + l15   (index algebra verified)
    const int srcLo = ((quad & 1) * 2) * 16 + l15;
    const int srcHi = srcLo + 16;
    const bool hiSel = (quad >> 1) != 0;
#pragma unroll
    for (int kk = 0; kk < 2; ++kk) {
      short8 av[2];
#pragma unroll
      for (int mb = 0; mb < 2; ++mb)
        av[mb] = *(const short8*)(Vt + (mb * 16 + l15) * 72 + kk * 32 + quad * 8);
#pragma unroll
      for (int nb = 0; nb < 4; ++nb) {
        const int ma = kk * 2, mbx = kk * 2 + 1;
        const u32 a0 = __shfl(pk[ma][nb][0], srcLo), b0 = __shfl(pk[mbx][nb][0], srcLo);
        const u32 a1 = __shfl(pk[ma][nb][1], srcLo), b1 = __shfl(pk[mbx][nb][1], srcLo);
        const u32 a2 = __shfl(pk[ma][nb][0], srcHi), b2 = __shfl(pk[mbx][nb][0], srcHi);
        const u32 a3 = __shfl(pk[ma][nb][1], srcHi), b3 = __shfl(pk[mbx][nb][1], srcHi);
        u32x4 tv = {hiSel ? b0 : a0, hiSel ? b1 : a1, hiSel ? b2 : a2, hiSel ? b3 : a3};
        const short8 pbv = __builtin_bit_cast(short8, tv);
        __builtin_amdgcn_s_setprio(1);
#pragma unroll
        for (int mb = 0; mb < 2; ++mb) ot[mb][nb] = mfma16(av[mb], pbv, ot[mb][nb]);
        __builtin_amdgcn_s_setprio(0);
      }
    }

    // O^T C-layout: row=dim=mb*16+quad*4+r, col=query=nb*16+l15 -> aoS[query][h*32+dim]
#pragma unroll
    for (int mb = 0; mb < 2; ++mb)
#pragma unroll
      for (int nb = 0; nb < 4; ++nb) {
        const u32 lo = (u32)f2bf(ot[mb][nb][0]) | ((u32)f2bf(ot[mb][nb][1]) << 16);
        const u32 hi2 = (u32)f2bf(ot[mb][nb][2]) | ((u32)f2bf(ot[mb][nb][3]) << 16);
        uint2 uv;
        uv.x = lo;
        uv.y = hi2;
        *(uint2*)(aoS + (nb * 16 + l15) * 392 + h * 32 + mb * 16 + quad * 4) = uv;
      }
  }

  __syncthreads();  // aoS complete across all waves

  // ---- proj GEMM: (64x384 from aoS) @ (384x384 pw)^T, wave wv owns cols wv*96..+96 ----
  floatx4 pacc[4][6];
#pragma unroll
  for (int mi = 0; mi < 4; ++mi)
#pragma unroll
    for (int nf = 0; nf < 6; ++nf) pacc[mi][nf] = z4;

  const u16* pwb = pw + (size_t)(wv * 96 + l15) * 384 + quad * 8;
#pragma unroll
  for (int kb = 0; kb < 12; ++kb) {
    short8 paf[4], pbf[6];
#pragma unroll
    for (int mi = 0; mi < 4; ++mi)
      paf[mi] = *(const short8*)(aoS + (mi * 16 + l15) * 392 + kb * 32 + quad * 8);
#pragma unroll
    for (int nf = 0; nf < 6; ++nf)
      pbf[nf] = *(const short8*)(pwb + nf * 6144 + kb * 32);
    __builtin_amdgcn_s_setprio(1);
#pragma unroll
    for (int mi = 0; mi < 4; ++mi)
#pragma unroll
      for (int nf = 0; nf < 6; ++nf)
        pacc[mi][nf] = mfma16(paf[mi], pbf[nf], pacc[mi][nf]);
    __builtin_amdgcn_s_setprio(0);
  }

#pragma unroll
  for (int nf = 0; nf < 6; ++nf) {
    const int col = wv * 96 + nf * 16 + l15;
    const float bb = pb[col];
#pragma unroll
    for (int mi = 0; mi < 4; ++mi)
#pragma unroll
      for (int r = 0; r < 4; ++r) {
        const int row = mi * 16 + quad * 4 + r;
        if (row < 49)
          out[((size_t)b * 49 + row) * 384 + col] = pacc[mi][nf][r] + bb;
      }
  }
}

// ---------------- launcher ----------------
extern "C" void kernel_launch(void* const* d_in, const int* in_sizes, int n_in,
                              void* d_out, int out_size, void* d_ws, size_t ws_size,
                              hipStream_t stream) {
  const float* x = (const float*)d_in[0];
  const float* mask = (const float*)d_in[1];
  const float* qkv_w = (const float*)d_in[2];
  const float* qkv_b = (const float*)d_in[3];
  const float* proj_w = (const float*)d_in[4];
  const float* proj_b = (const float*)d_in[5];
  const float* bias_table = (const float*)d_in[6];
  float* out = (float*)d_out;
  char* ws = (char*)d_ws;

  u16* wb1 = (u16*)(ws);                        // 442368 bf16 = 884736 B
  u16* wb2 = (u16*)(ws + 884736);               // 147456 bf16 = 294912 B
  float* comb = (float*)(ws + 1179648);         // 768*4096 f32 = 12582912 B
  u16* qkvb = (u16*)(ws + 13762560);            // 200704*1152 bf16 = 462422016 B (head-major)
  u16* xb = (u16*)(ws + 476184576);             // 200704*384 bf16 = 154140672 B
  // total ws use: 630325248 B

  hipLaunchKernelGGL(cast_w_kernel, dim3(1728), dim3(256), 0, stream, qkv_w, proj_w, wb1, wb2);
  hipLaunchKernelGGL(cast_x_kernel, dim3(37632), dim3(256), 0, stream, x, xb);
  hipLaunchKernelGGL(comb_kernel, dim3(768), dim3(256), 0, stream, bias_table, mask, comb);
  hipLaunchKernelGGL(qkv_gemm, dim3(14112), dim3(256), 0, stream, xb, wb1, qkv_b, qkvb);
  hipLaunchKernelGGL(attn_proj, dim3(4096), dim3(256), 0, stream, qkvb, comb, wb2, proj_b, out);
}

// Round 5
// 1148.473 us; speedup vs baseline: 1.2420x; 1.0396x over previous
//
#include <hip/hip_runtime.h>

typedef unsigned short u16;
typedef unsigned int u32;
typedef __attribute__((ext_vector_type(8))) short short8;
typedef __attribute__((ext_vector_type(4))) float floatx4;
typedef __attribute__((ext_vector_type(4))) unsigned int u32x4;

#define SCALE_Q 0.17677669529663687f  // 32^-0.5

__device__ __forceinline__ u16 f2bf(float f) {
  u32 u = __float_as_uint(f);
  u = (u + 0x7fffu + ((u >> 16) & 1u)) >> 16;
  return (u16)u;
}

__device__ __forceinline__ u32 pk2bf(float lo, float hi) {
  return (u32)f2bf(lo) | ((u32)f2bf(hi) << 16);
}

__device__ __forceinline__ void gload_lds16(const void* g, void* l) {
  __builtin_amdgcn_global_load_lds(
      (const __attribute__((address_space(1))) u32*)g,
      (__attribute__((address_space(3))) u32*)l, 16, 0, 0);
}

__device__ __forceinline__ floatx4 mfma16(short8 a, short8 b, floatx4 c) {
  return __builtin_amdgcn_mfma_f32_16x16x32_bf16(a, b, c, 0, 0, 0);
}

// ---------------- prep: cast weights to bf16 ----------------
__global__ void cast_w_kernel(const float* __restrict__ qkv_w,
                              const float* __restrict__ proj_w,
                              u16* __restrict__ wb1, u16* __restrict__ wb2) {
  int idx = blockIdx.x * 256 + threadIdx.x;   // grid covers 442368 exactly
  wb1[idx] = f2bf(qkv_w[idx]);
  if (idx < 147456) wb2[idx] = f2bf(proj_w[idx]);
}

// ---- prep: combined bias+mask table: comb[w][h][query(64)][key(64)] ----
__global__ void comb_kernel(const float* __restrict__ bias_table,
                            const float* __restrict__ mask,
                            float* __restrict__ comb) {
  int wh = blockIdx.x;          // 768 = 64 windows * 12 heads
  int w = wh / 12, h = wh - w * 12;
  float* dst = comb + (size_t)wh * 4096;
  for (int e = threadIdx.x; e < 4096; e += 256) {
    int p = e >> 6, q = e & 63;   // p = query token, q = key token
    float v;
    if (q >= 49) v = -1e30f;          // padded key columns -> softmax zero
    else if (p >= 49) v = 0.0f;       // padded query rows: keep finite
    else {
      int pi = p / 7, pj = p - pi * 7;
      int qi = q / 7, qj = q - qi * 7;
      int ridx = (pi - qi + 6) * 13 + (pj - qj + 6);
      v = bias_table[ridx * 12 + h] + mask[(size_t)w * 2401 + p * 49 + q];
    }
    dst[e] = v;                       // e = query*64 + key
  }
}

// ---------------- QKV GEMM with FUSED x cast: (200704x384 fp32) @ (1152x384 bf16)^T ----
// Single-buffer stage->sync->compute->sync (R0's measured-fastest structure) +
// XOR k-chunk LDS swizzle (conflict-free reads) + head-major bf16 output.
// A operand: fp32 from x, reg-staged (loads hoisted one iteration, T14) -> cvt -> ds_write.
// B operand: bf16 weights via global_load_lds (unchanged, coalesced + XOR).
__global__ __launch_bounds__(256) void qkv_gemm(const float* __restrict__ X,
                                                const u16* __restrict__ B,
                                                const float* __restrict__ bias,
                                                u16* __restrict__ C) {
  __shared__ u16 As[4096];  // 8KB: [m(128)][kchunk(4, XOR-permuted)][8]
  __shared__ u16 Bs[4096];
  const int tid = threadIdx.x;
  const int lane = tid & 63;
  const int wave = tid >> 6;
  const int l15 = lane & 15;
  const int quad = lane >> 4;
  const int wr = wave >> 1, wc = wave & 1;
  // swizzle: grid 14112 = 8 xcd * 196 grp * 9 tn
  const u32 bid = blockIdx.x;
  const u32 xcd = bid & 7;
  const u32 slot = bid >> 3;        // 0..1763
  const u32 grp = slot / 9;
  const u32 tn = slot - grp * 9;
  const u32 tm = xcd * 196 + grp;   // 0..1567

  // A reg-staging: thread -> row mA = tid>>1, 16 floats at col hA*16 (+kb*32)
  const int mA = tid >> 1, hA = tid & 1;
  const float* Axp = X + (size_t)(tm * 128 + mA) * 384 + hA * 16;
  const int mskA = (mA >> 1) & 3;
  const int sA0 = (mA * 4 + ((hA * 2) ^ mskA)) * 8;      // u16 index of 16B slot
  const int sA1 = (mA * 4 + ((hA * 2 + 1) ^ mskA)) * 8;

  // B staging map: 16B slot c holds B[m=c>>2][kp*8..) with kp = (c&3)^((m>>1)&3)
  const int c0 = tid, c1 = tid + 256;
  const int m0 = c0 >> 2, kp0 = (c0 & 3) ^ ((m0 >> 1) & 3);
  const int m1 = c1 >> 2, kp1 = (c1 & 3) ^ ((m1 >> 1) & 3);
  const u16* Bb0 = B + (size_t)(tn * 128 + m0) * 384 + kp0 * 8;
  const u16* Bb1 = B + (size_t)(tn * 128 + m1) * 384 + kp1 * 8;
  const int ld0 = c0 * 8, ld1 = c1 * 8;

  floatx4 acc[4][4];
#pragma unroll
  for (int i = 0; i < 4; ++i)
#pragma unroll
    for (int j = 0; j < 4; ++j) acc[i][j] = (floatx4){0.f, 0.f, 0.f, 0.f};

  // prefetch A regs for kb=0
  float4 ar0 = *(const float4*)(Axp + 0);
  float4 ar1 = *(const float4*)(Axp + 4);
  float4 ar2 = *(const float4*)(Axp + 8);
  float4 ar3 = *(const float4*)(Axp + 12);

  // read-side XOR: row = wr*64+i*16+l15 -> ((row>>1)&3) == ((l15>>1)&3)
  const int xq = quad ^ ((l15 >> 1) & 3);
  const int abase = (wr * 64 + l15) * 32 + xq * 8;
  const int bbase = (wc * 64 + l15) * 32 + xq * 8;

  for (int kb = 0; kb < 12; ++kb) {
    if (kb) __syncthreads();          // prior compute done; LDS reusable
    const int k0 = kb * 32;
    gload_lds16(Bb0 + k0, &Bs[ld0]);
    gload_lds16(Bb1 + k0, &Bs[ld1]);
    // convert current A regs -> LDS (two 16B slots)
    uint4 pA0, pA1;
    pA0.x = pk2bf(ar0.x, ar0.y);
    pA0.y = pk2bf(ar0.z, ar0.w);
    pA0.z = pk2bf(ar1.x, ar1.y);
    pA0.w = pk2bf(ar1.z, ar1.w);
    pA1.x = pk2bf(ar2.x, ar2.y);
    pA1.y = pk2bf(ar2.z, ar2.w);
    pA1.z = pk2bf(ar3.x, ar3.y);
    pA1.w = pk2bf(ar3.z, ar3.w);
    *(uint4*)(&As[sA0]) = pA0;
    *(uint4*)(&As[sA1]) = pA1;
    // hoist next iteration's A loads (drained at the barrier together with B)
    if (kb < 11) {
      const float* nx = Axp + (kb + 1) * 32;
      ar0 = *(const float4*)(nx + 0);
      ar1 = *(const float4*)(nx + 4);
      ar2 = *(const float4*)(nx + 8);
      ar3 = *(const float4*)(nx + 12);
    }
    __syncthreads();                  // drains B gload + A ds_writes (+ hoisted loads)
    short8 af[4], bfr[4];
#pragma unroll
    for (int i = 0; i < 4; ++i)
      af[i] = *(const short8*)(&As[abase + i * 512]);
#pragma unroll
    for (int i = 0; i < 4; ++i)
      bfr[i] = *(const short8*)(&Bs[bbase + i * 512]);
#pragma unroll
    for (int mi = 0; mi < 4; ++mi)
#pragma unroll
      for (int ni = 0; ni < 4; ++ni)
        acc[mi][ni] = mfma16(af[mi], bfr[ni], acc[mi][ni]);
  }

  // epilogue: +bias, fold SCALE into q; head-major output layout
#pragma unroll
  for (int ni = 0; ni < 4; ++ni) {
    const int gbase = (int)tn * 128 + wc * 64 + ni * 16;   // 16-aligned, no head crossing
    const int which = gbase / 384;
    const int rem = gbase - which * 384;
    const int h = rem >> 5;
    const int db = rem & 31;
    const float bb = bias[gbase + l15];
    const float scale = (which == 0) ? SCALE_Q : 1.0f;
    u16* hp = C + ((size_t)which * 49152 + h) * 1568 + db + l15;
#pragma unroll
    for (int mi = 0; mi < 4; ++mi) {
      const int grow0 = (int)tm * 128 + wr * 64 + mi * 16 + quad * 4;
#pragma unroll
      for (int r = 0; r < 4; ++r) {
        const int grow = grow0 + r;
        const int b = grow / 49;
        const int tok = grow - b * 49;
        hp[(size_t)b * 18816 + tok * 32] = f2bf((acc[mi][ni][r] + bb) * scale);
      }
    }
  }
}

// ---------------- fused attention+proj: one block (4 waves) per window ----------------
// Swapped QK^T (St = mfma(K,Q)), lane-local softmax, shfl P^T transpose (no Ps LDS).
// NEW: next-head register prefetch (T14) — head hi+1's Q/K/V loads are issued at the
// top of head hi's compute, hiding the global-load chain that dominated R4's time.
// LDS: aoS 50176 + 4x Vt 4608 = 68608 B -> 2 blocks/CU.
__global__ __launch_bounds__(256, 2) void attn_proj(const u16* __restrict__ qkv,
                                                    const float* __restrict__ comb,
                                                    const u16* __restrict__ pw,
                                                    const float* __restrict__ pb,
                                                    float* __restrict__ out) {
  __shared__ uint4 smem[4288];                              // 68608 B
  u16* aoS = (u16*)smem;                                    // [64][392]
  const int tid = threadIdx.x;
  const int lane = tid & 63;
  const int wv = tid >> 6;
  const int l15 = lane & 15, quad = lane >> 4;
  u16* Vt = (u16*)((char*)smem + 50176 + wv * 4608);        // [32][72] per wave

  const int bid = blockIdx.x;
  const int w = bid >> 6;                                   // comb slice shared in L2
  const int b = (bid & 63) * 64 + w;                        // b & 63 == w

  const floatx4 z4 = (floatx4){0.f, 0.f, 0.f, 0.f};
  const short8 z8 = {0, 0, 0, 0, 0, 0, 0, 0};

  // V slot geometry (lane-constant): slots svi=0..2 -> tokens (lane>>2)+svi*16,
  // slot 3 -> token 48 clamped (lanes >=4 are pad tokens 49..63, value zeroed on write).
  const int vcol = (lane & 3) * 8;
  const int vrow = lane >> 2;
  const int voff0 = vrow * 32 + vcol;

  // double register sets for head pipeline
  short8 aqR[2][4], bkR[2][4];
  uint4 vvR[2][4];

#define LOADH(HH, RR)                                                          \
  do {                                                                         \
    const int h_ = wv + (HH) * 4;                                              \
    const size_t ho_ = (size_t)(b * 12 + h_) * 1568;                           \
    const u16* qb_ = qkv + ho_;                                                \
    const u16* kb_ = qkv + (size_t)49152 * 1568 + ho_;                         \
    const u16* vb_ = qkv + (size_t)98304 * 1568 + ho_;                         \
    _Pragma("unroll") for (int i_ = 0; i_ < 3; ++i_) {                         \
      aqR[RR][i_] = *(const short8*)(qb_ + (i_ * 16 + l15) * 32 + quad * 8);   \
      bkR[RR][i_] = *(const short8*)(kb_ + (i_ * 16 + l15) * 32 + quad * 8);   \
    }                                                                          \
    aqR[RR][3] = (l15 == 0) ? *(const short8*)(qb_ + 48 * 32 + quad * 8) : z8; \
    bkR[RR][3] = (l15 == 0) ? *(const short8*)(kb_ + 48 * 32 + quad * 8) : z8; \
    vvR[RR][0] = *(const uint4*)(vb_ + voff0);                                 \
    vvR[RR][1] = *(const uint4*)(vb_ + voff0 + 16 * 32);                       \
    vvR[RR][2] = *(const uint4*)(vb_ + voff0 + 32 * 32);                       \
    vvR[RR][3] = *(const uint4*)(vb_ + 48 * 32 + vcol);                        \
  } while (0)

  LOADH(0, 0);

#pragma unroll
  for (int hi = 0; hi < 3; ++hi) {
    const int cu = hi & 1;
    const int h = wv + hi * 4;
    if (hi < 2) {
      if (hi == 0) LOADH(1, 1);
      else LOADH(2, 0);
    }

    // Vt write from current V regs (pad tokens zeroed)
#pragma unroll
    for (int svi = 0; svi < 4; ++svi) {
      uint4 dv = vvR[cu][svi];
      const int t = vrow + svi * 16;             // svi=3: 48..63
      if (svi == 3 && lane >= 4) dv = make_uint4(0u, 0u, 0u, 0u);
      const int d0 = (lane & 3) * 8;
      const u32 vvx[4] = {dv.x, dv.y, dv.z, dv.w};
#pragma unroll
      for (int e = 0; e < 4; ++e) {
        Vt[(d0 + 2 * e) * 72 + t] = (u16)(vvx[e] & 0xffffu);
        Vt[(d0 + 2 * e + 1) * 72 + t] = (u16)(vvx[e] >> 16);
      }
    }

    // St = K Q^T (swapped): row=key=mi*16+quad*4+r, col=query=ni*16+l15
    floatx4 st[4][4];
    __builtin_amdgcn_s_setprio(1);
#pragma unroll
    for (int mi = 0; mi < 4; ++mi)
#pragma unroll
      for (int ni = 0; ni < 4; ++ni) st[mi][ni] = mfma16(bkR[cu][mi], aqR[cu][ni], z4);
    __builtin_amdgcn_s_setprio(0);

    // comb[w][h][query][key]: float4 over key/reg axis
    const float* cb = comb + (size_t)(w * 12 + h) * 4096;
#pragma unroll
    for (int ni = 0; ni < 4; ++ni)
#pragma unroll
      for (int mi = 0; mi < 4; ++mi) {
        const float4 cv = *(const float4*)(cb + (ni * 16 + l15) * 64 + mi * 16 + quad * 4);
        st[mi][ni][0] += cv.x;
        st[mi][ni][1] += cv.y;
        st[mi][ni][2] += cv.z;
        st[mi][ni][3] += cv.w;
      }

    // softmax over keys: 16 lane-local + cross-quad shfl
    float rinv[4];
#pragma unroll
    for (int ni = 0; ni < 4; ++ni) {
      float mx = st[0][ni][0];
#pragma unroll
      for (int mi = 0; mi < 4; ++mi)
#pragma unroll
        for (int r = 0; r < 4; ++r) mx = fmaxf(mx, st[mi][ni][r]);
      mx = fmaxf(mx, __shfl_xor(mx, 16));
      mx = fmaxf(mx, __shfl_xor(mx, 32));
      float sum = 0.f;
#pragma unroll
      for (int mi = 0; mi < 4; ++mi)
#pragma unroll
        for (int r = 0; r < 4; ++r) {
          const float e = __expf(st[mi][ni][r] - mx);
          st[mi][ni][r] = e;
          sum += e;
        }
      sum += __shfl_xor(sum, 16);
      sum += __shfl_xor(sum, 32);
      rinv[ni] = 1.0f / sum;
    }

    // pack P^T to bf16 pairs: pk[mi][ni][t] = keys (mi*16+quad*4+2t, +1), query (ni,l15)
    u32 pk[4][4][2];
#pragma unroll
    for (int mi = 0; mi < 4; ++mi)
#pragma unroll
      for (int ni = 0; ni < 4; ++ni)
#pragma unroll
        for (int t = 0; t < 2; ++t)
          pk[mi][ni][t] = pk2bf(st[mi][ni][2 * t] * rinv[ni],
                                st[mi][ni][2 * t + 1] * rinv[ni]);

    // O^T = V^T P^T : M=32 dims (mb), N=64 queries (nb), K=64 keys (kk)
    floatx4 ot[2][4];
#pragma unroll
    for (int mb = 0; mb < 2; ++mb)
#pragma unroll
      for (int nb = 0; nb < 4; ++nb) ot[mb][nb] = z4;

    const int srcLo = ((quad & 1) * 2) * 16 + l15;
    const int srcHi = srcLo + 16;
    const bool hiSel = (quad >> 1) != 0;
#pragma unroll
    for (int kk = 0; kk < 2; ++kk) {
      short8 av[2];
#pragma unroll
      for (int mb = 0; mb < 2; ++mb)
        av[mb] = *(const short8*)(Vt + (mb * 16 + l15) * 72 + kk * 32 + quad * 8);
#pragma unroll
      for (int nb = 0; nb < 4; ++nb) {
        const int ma = kk * 2, mbx = kk * 2 + 1;
        const u32 a0 = __shfl(pk[ma][nb][0], srcLo), b0 = __shfl(pk[mbx][nb][0], srcLo);
        const u32 a1 = __shfl(pk[ma][nb][1], srcLo), b1 = __shfl(pk[mbx][nb][1], srcLo);
        const u32 a2 = __shfl(pk[ma][nb][0], srcHi), b2 = __shfl(pk[mbx][nb][0], srcHi);
        const u32 a3 = __shfl(pk[ma][nb][1], srcHi), b3 = __shfl(pk[mbx][nb][1], srcHi);
        u32x4 tv = {hiSel ? b0 : a0, hiSel ? b1 : a1, hiSel ? b2 : a2, hiSel ? b3 : a3};
        const short8 pbv = __builtin_bit_cast(short8, tv);
        __builtin_amdgcn_s_setprio(1);
#pragma unroll
        for (int mb = 0; mb < 2; ++mb) ot[mb][nb] = mfma16(av[mb], pbv, ot[mb][nb]);
        __builtin_amdgcn_s_setprio(0);
      }
    }

    // O^T: row=dim=mb*16+quad*4+r, col=query=nb*16+l15 -> aoS[query][h*32+dim]
#pragma unroll
    for (int mb = 0; mb < 2; ++mb)
#pragma unroll
      for (int nb = 0; nb < 4; ++nb) {
        uint2 uv;
        uv.x = pk2bf(ot[mb][nb][0], ot[mb][nb][1]);
        uv.y = pk2bf(ot[mb][nb][2], ot[mb][nb][3]);
        *(uint2*)(aoS + (nb * 16 + l15) * 392 + h * 32 + mb * 16 + quad * 4) = uv;
      }
  }
#undef LOADH

  __syncthreads();  // aoS complete across all waves

  // ---- proj GEMM: (64x384 from aoS) @ (384x384 pw)^T, wave wv owns cols wv*96..+96 ----
  floatx4 pacc[4][6];
#pragma unroll
  for (int mi = 0; mi < 4; ++mi)
#pragma unroll
    for (int nf = 0; nf < 6; ++nf) pacc[mi][nf] = z4;

  const u16* pwb = pw + (size_t)(wv * 96 + l15) * 384 + quad * 8;
#pragma unroll
  for (int kb = 0; kb < 12; ++kb) {
    short8 paf[4], pbf[6];
#pragma unroll
    for (int mi = 0; mi < 4; ++mi)
      paf[mi] = *(const short8*)(aoS + (mi * 16 + l15) * 392 + kb * 32 + quad * 8);
#pragma unroll
    for (int nf = 0; nf < 6; ++nf)
      pbf[nf] = *(const short8*)(pwb + nf * 6144 + kb * 32);
    __builtin_amdgcn_s_setprio(1);
#pragma unroll
    for (int mi = 0; mi < 4; ++mi)
#pragma unroll
      for (int nf = 0; nf < 6; ++nf)
        pacc[mi][nf] = mfma16(paf[mi], pbf[nf], pacc[mi][nf]);
    __builtin_amdgcn_s_setprio(0);
  }

#pragma unroll
  for (int nf = 0; nf < 6; ++nf) {
    const int col = wv * 96 + nf * 16 + l15;
    const float bb = pb[col];
#pragma unroll
    for (int mi = 0; mi < 4; ++mi)
#pragma unroll
      for (int r = 0; r < 4; ++r) {
        const int row = mi * 16 + quad * 4 + r;
        if (row < 49)
          out[((size_t)b * 49 + row) * 384 + col] = pacc[mi][nf][r] + bb;
      }
  }
}

// ---------------- launcher ----------------
extern "C" void kernel_launch(void* const* d_in, const int* in_sizes, int n_in,
                              void* d_out, int out_size, void* d_ws, size_t ws_size,
                              hipStream_t stream) {
  const float* x = (const float*)d_in[0];
  const float* mask = (const float*)d_in[1];
  const float* qkv_w = (const float*)d_in[2];
  const float* qkv_b = (const float*)d_in[3];
  const float* proj_w = (const float*)d_in[4];
  const float* proj_b = (const float*)d_in[5];
  const float* bias_table = (const float*)d_in[6];
  float* out = (float*)d_out;
  char* ws = (char*)d_ws;

  u16* wb1 = (u16*)(ws);                        // 442368 bf16 = 884736 B
  u16* wb2 = (u16*)(ws + 884736);               // 147456 bf16 = 294912 B
  float* comb = (float*)(ws + 1179648);         // 768*4096 f32 = 12582912 B
  u16* qkvb = (u16*)(ws + 13762560);            // 200704*1152 bf16 = 462422016 B (head-major)
  // x is cast in-kernel now; xb buffer eliminated. total ws use: 476184576 B

  hipLaunchKernelGGL(cast_w_kernel, dim3(1728), dim3(256), 0, stream, qkv_w, proj_w, wb1, wb2);
  hipLaunchKernelGGL(comb_kernel, dim3(768), dim3(256), 0, stream, bias_table, mask, comb);
  hipLaunchKernelGGL(qkv_gemm, dim3(14112), dim3(256), 0, stream, x, wb1, qkv_b, qkvb);
  hipLaunchKernelGGL(attn_proj, dim3(4096), dim3(256), 0, stream, qkvb, comb, wb2, proj_b, out);
}

// Round 6
// 1079.041 us; speedup vs baseline: 1.3219x; 1.0643x over previous
//
#include <hip/hip_runtime.h>

typedef unsigned short u16;
typedef unsigned int u32;
typedef __attribute__((ext_vector_type(8))) short short8;
typedef __attribute__((ext_vector_type(4))) float floatx4;
typedef __attribute__((ext_vector_type(4))) unsigned int u32x4;

#define SCALE_Q 0.17677669529663687f  // 32^-0.5

__device__ __forceinline__ u16 f2bf(float f) {
  u32 u = __float_as_uint(f);
  u = (u + 0x7fffu + ((u >> 16) & 1u)) >> 16;
  return (u16)u;
}

__device__ __forceinline__ u32 pk2bf(float lo, float hi) {
  return (u32)f2bf(lo) | ((u32)f2bf(hi) << 16);
}

// HW packed fp32->bf16 (RNE), 1 instr per 2 floats (T12 recipe; no builtin on gfx950)
__device__ __forceinline__ u32 cvtpk(float lo, float hi) {
  u32 r;
  asm("v_cvt_pk_bf16_f32 %0, %1, %2" : "=v"(r) : "v"(lo), "v"(hi));
  return r;
}

__device__ __forceinline__ void gload_lds16(const void* g, void* l) {
  __builtin_amdgcn_global_load_lds(
      (const __attribute__((address_space(1))) u32*)g,
      (__attribute__((address_space(3))) u32*)l, 16, 0, 0);
}

__device__ __forceinline__ floatx4 mfma16(short8 a, short8 b, floatx4 c) {
  return __builtin_amdgcn_mfma_f32_16x16x32_bf16(a, b, c, 0, 0, 0);
}

// ---------------- prep: cast weights to bf16 ----------------
__global__ void cast_w_kernel(const float* __restrict__ qkv_w,
                              const float* __restrict__ proj_w,
                              u16* __restrict__ wb1, u16* __restrict__ wb2) {
  int idx = blockIdx.x * 256 + threadIdx.x;   // grid covers 442368 exactly
  wb1[idx] = f2bf(qkv_w[idx]);
  if (idx < 147456) wb2[idx] = f2bf(proj_w[idx]);
}

// ---- prep: combined bias+mask table: comb[w][h][query(64)][key(64)] ----
__global__ void comb_kernel(const float* __restrict__ bias_table,
                            const float* __restrict__ mask,
                            float* __restrict__ comb) {
  int wh = blockIdx.x;          // 768 = 64 windows * 12 heads
  int w = wh / 12, h = wh - w * 12;
  float* dst = comb + (size_t)wh * 4096;
  for (int e = threadIdx.x; e < 4096; e += 256) {
    int p = e >> 6, q = e & 63;   // p = query token, q = key token
    float v;
    if (q >= 49) v = -1e30f;          // padded key columns -> softmax zero
    else if (p >= 49) v = 0.0f;       // padded query rows: keep finite
    else {
      int pi = p / 7, pj = p - pi * 7;
      int qi = q / 7, qj = q - qi * 7;
      int ridx = (pi - qi + 6) * 13 + (pj - qj + 6);
      v = bias_table[ridx * 12 + h] + mask[(size_t)w * 2401 + p * 49 + q];
    }
    dst[e] = v;                       // e = query*64 + key
  }
}

// ---------------- QKV GEMM with FUSED x cast: (200704x384 fp32) @ (1152x384 bf16)^T ----
// Single-buffer stage->sync->compute->sync (R0's measured-fastest structure).
// A: fp32 reg-staged COALESCED (slot s=tid+256j -> row s>>3, chunk s&7: 8 lanes = one
// full 128B line), cast via v_cvt_pk_bf16_f32 (8 ops/thread/iter), 2x ds_write_b64 into
// the XOR-swizzled [m][kp^msk][8] layout. Next-iter A loads issued AFTER the mid
// barrier so they drain at the NEXT top barrier (hidden under MFMA compute).
// B: bf16 weights via global_load_lds (coalesced + XOR). Head-major bf16 output.
__global__ __launch_bounds__(256) void qkv_gemm(const float* __restrict__ X,
                                                const u16* __restrict__ B,
                                                const float* __restrict__ bias,
                                                u16* __restrict__ C) {
  __shared__ u16 As[4096];  // 8KB: [m(128)][kchunk(4, XOR-permuted)][8]
  __shared__ u16 Bs[4096];
  const int tid = threadIdx.x;
  const int lane = tid & 63;
  const int wave = tid >> 6;
  const int l15 = lane & 15;
  const int quad = lane >> 4;
  const int wr = wave >> 1, wc = wave & 1;
  // swizzle: grid 14112 = 8 xcd * 196 grp * 9 tn
  const u32 bid = blockIdx.x;
  const u32 xcd = bid & 7;
  const u32 slot = bid >> 3;        // 0..1763
  const u32 grp = slot / 9;
  const u32 tn = slot - grp * 9;
  const u32 tm = xcd * 196 + grp;   // 0..1567

  // A staging: slot s = tid + 256*j -> row m = s>>3 (= mA+32j), float4 chunk c4 = s&7.
  // 8 lanes cover one row's 32 floats = 128B line. LDS: kp = (c4>>1)^msk, half = c4&1.
  const int mA = tid >> 3;
  const int c4 = tid & 7;
  const float* Axp = X + (size_t)(tm * 128 + mA) * 384 + c4 * 4;
  const int mskA = (mA >> 1) & 3;    // ((mA+32j)>>1)&3 == (mA>>1)&3 (32j keeps bits 1..2)
  const int sBase = mA * 32 + ((c4 >> 1) ^ mskA) * 8 + (c4 & 1) * 4;  // u16 idx; +1024/j

  // B staging map: 16B slot c holds B[m=c>>2][kp*8..) with kp = (c&3)^((m>>1)&3)
  const int c0 = tid, c1 = tid + 256;
  const int m0 = c0 >> 2, kp0 = (c0 & 3) ^ ((m0 >> 1) & 3);
  const int m1 = c1 >> 2, kp1 = (c1 & 3) ^ ((m1 >> 1) & 3);
  const u16* Bb0 = B + (size_t)(tn * 128 + m0) * 384 + kp0 * 8;
  const u16* Bb1 = B + (size_t)(tn * 128 + m1) * 384 + kp1 * 8;
  const int ld0 = c0 * 8, ld1 = c1 * 8;

  floatx4 acc[4][4];
#pragma unroll
  for (int i = 0; i < 4; ++i)
#pragma unroll
    for (int j = 0; j < 4; ++j) acc[i][j] = (floatx4){0.f, 0.f, 0.f, 0.f};

  // prefetch A regs for kb=0
  float4 ar[4];
#pragma unroll
  for (int j = 0; j < 4; ++j) ar[j] = *(const float4*)(Axp + 12288 * j);

  // read-side XOR: row = wr*64+i*16+l15 -> ((row>>1)&3) == ((l15>>1)&3)
  const int xq = quad ^ ((l15 >> 1) & 3);
  const int abase = (wr * 64 + l15) * 32 + xq * 8;
  const int bbase = (wc * 64 + l15) * 32 + xq * 8;

  for (int kb = 0; kb < 12; ++kb) {
    if (kb) __syncthreads();          // prior compute done; LDS reusable
    const int k0 = kb * 32;
    gload_lds16(Bb0 + k0, &Bs[ld0]);
    gload_lds16(Bb1 + k0, &Bs[ld1]);
    // cast current A regs -> LDS (ds_write_b64 x4, 2-way bank aliasing = free)
#pragma unroll
    for (int j = 0; j < 4; ++j) {
      uint2 w2;
      w2.x = cvtpk(ar[j].x, ar[j].y);
      w2.y = cvtpk(ar[j].z, ar[j].w);
      *(uint2*)(&As[sBase + 1024 * j]) = w2;
    }
    __syncthreads();                  // drains B gload + A ds_writes
    // issue next-iter A loads now: drained by NEXT top barrier, hidden under MFMAs
    if (kb < 11) {
#pragma unroll
      for (int j = 0; j < 4; ++j)
        ar[j] = *(const float4*)(Axp + 12288 * j + (kb + 1) * 32);
    }
    short8 af[4], bfr[4];
#pragma unroll
    for (int i = 0; i < 4; ++i)
      af[i] = *(const short8*)(&As[abase + i * 512]);
#pragma unroll
    for (int i = 0; i < 4; ++i)
      bfr[i] = *(const short8*)(&Bs[bbase + i * 512]);
#pragma unroll
    for (int mi = 0; mi < 4; ++mi)
#pragma unroll
      for (int ni = 0; ni < 4; ++ni)
        acc[mi][ni] = mfma16(af[mi], bfr[ni], acc[mi][ni]);
  }

  // epilogue: +bias, fold SCALE into q; head-major output layout
#pragma unroll
  for (int ni = 0; ni < 4; ++ni) {
    const int gbase = (int)tn * 128 + wc * 64 + ni * 16;   // 16-aligned, no head crossing
    const int which = gbase / 384;
    const int rem = gbase - which * 384;
    const int h = rem >> 5;
    const int db = rem & 31;
    const float bb = bias[gbase + l15];
    const float scale = (which == 0) ? SCALE_Q : 1.0f;
    u16* hp = C + ((size_t)which * 49152 + h) * 1568 + db + l15;
#pragma unroll
    for (int mi = 0; mi < 4; ++mi) {
      const int grow0 = (int)tm * 128 + wr * 64 + mi * 16 + quad * 4;
#pragma unroll
      for (int r = 0; r < 4; ++r) {
        const int grow = grow0 + r;
        const int b = grow / 49;
        const int tok = grow - b * 49;
        hp[(size_t)b * 18816 + tok * 32] = f2bf((acc[mi][ni][r] + bb) * scale);
      }
    }
  }
}

// ---------------- fused attention+proj: one block (4 waves) per window ----------------
// Swapped QK^T (St = mfma(K,Q)), lane-local softmax, shfl P^T transpose (no Ps LDS),
// next-head register prefetch (T14). LDS: aoS 50176 + 4x Vt 4608 = 68608 B -> 2 blk/CU.
// (unchanged from R5 — measured improvement)
__global__ __launch_bounds__(256, 2) void attn_proj(const u16* __restrict__ qkv,
                                                    const float* __restrict__ comb,
                                                    const u16* __restrict__ pw,
                                                    const float* __restrict__ pb,
                                                    float* __restrict__ out) {
  __shared__ uint4 smem[4288];                              // 68608 B
  u16* aoS = (u16*)smem;                                    // [64][392]
  const int tid = threadIdx.x;
  const int lane = tid & 63;
  const int wv = tid >> 6;
  const int l15 = lane & 15, quad = lane >> 4;
  u16* Vt = (u16*)((char*)smem + 50176 + wv * 4608);        // [32][72] per wave

  const int bid = blockIdx.x;
  const int w = bid >> 6;                                   // comb slice shared in L2
  const int b = (bid & 63) * 64 + w;                        // b & 63 == w

  const floatx4 z4 = (floatx4){0.f, 0.f, 0.f, 0.f};
  const short8 z8 = {0, 0, 0, 0, 0, 0, 0, 0};

  // V slot geometry (lane-constant): slots svi=0..2 -> tokens (lane>>2)+svi*16,
  // slot 3 -> token 48 clamped (lanes >=4 are pad tokens 49..63, value zeroed on write).
  const int vcol = (lane & 3) * 8;
  const int vrow = lane >> 2;
  const int voff0 = vrow * 32 + vcol;

  // double register sets for head pipeline
  short8 aqR[2][4], bkR[2][4];
  uint4 vvR[2][4];

#define LOADH(HH, RR)                                                          \
  do {                                                                         \
    const int h_ = wv + (HH) * 4;                                              \
    const size_t ho_ = (size_t)(b * 12 + h_) * 1568;                           \
    const u16* qb_ = qkv + ho_;                                                \
    const u16* kb_ = qkv + (size_t)49152 * 1568 + ho_;                         \
    const u16* vb_ = qkv + (size_t)98304 * 1568 + ho_;                         \
    _Pragma("unroll") for (int i_ = 0; i_ < 3; ++i_) {                         \
      aqR[RR][i_] = *(const short8*)(qb_ + (i_ * 16 + l15) * 32 + quad * 8);   \
      bkR[RR][i_] = *(const short8*)(kb_ + (i_ * 16 + l15) * 32 + quad * 8);   \
    }                                                                          \
    aqR[RR][3] = (l15 == 0) ? *(const short8*)(qb_ + 48 * 32 + quad * 8) : z8; \
    bkR[RR][3] = (l15 == 0) ? *(const short8*)(kb_ + 48 * 32 + quad * 8) : z8; \
    vvR[RR][0] = *(const uint4*)(vb_ + voff0);                                 \
    vvR[RR][1] = *(const uint4*)(vb_ + voff0 + 16 * 32);                       \
    vvR[RR][2] = *(const uint4*)(vb_ + voff0 + 32 * 32);                       \
    vvR[RR][3] = *(const uint4*)(vb_ + 48 * 32 + vcol);                        \
  } while (0)

  LOADH(0, 0);

#pragma unroll
  for (int hi = 0; hi < 3; ++hi) {
    const int cu = hi & 1;
    const int h = wv + hi * 4;
    if (hi < 2) {
      if (hi == 0) LOADH(1, 1);
      else LOADH(2, 0);
    }

    // Vt write from current V regs (pad tokens zeroed)
#pragma unroll
    for (int svi = 0; svi < 4; ++svi) {
      uint4 dv = vvR[cu][svi];
      const int t = vrow + svi * 16;             // svi=3: 48..63
      if (svi == 3 && lane >= 4) dv = make_uint4(0u, 0u, 0u, 0u);
      const int d0 = (lane & 3) * 8;
      const u32 vvx[4] = {dv.x, dv.y, dv.z, dv.w};
#pragma unroll
      for (int e = 0; e < 4; ++e) {
        Vt[(d0 + 2 * e) * 72 + t] = (u16)(vvx[e] & 0xffffu);
        Vt[(d0 + 2 * e + 1) * 72 + t] = (u16)(vvx[e] >> 16);
      }
    }

    // St = K Q^T (swapped): row=key=mi*16+quad*4+r, col=query=ni*16+l15
    floatx4 st[4][4];
    __builtin_amdgcn_s_setprio(1);
#pragma unroll
    for (int mi = 0; mi < 4; ++mi)
#pragma unroll
      for (int ni = 0; ni < 4; ++ni) st[mi][ni] = mfma16(bkR[cu][mi], aqR[cu][ni], z4);
    __builtin_amdgcn_s_setprio(0);

    // comb[w][h][query][key]: float4 over key/reg axis
    const float* cb = comb + (size_t)(w * 12 + h) * 4096;
#pragma unroll
    for (int ni = 0; ni < 4; ++ni)
#pragma unroll
      for (int mi = 0; mi < 4; ++mi) {
        const float4 cv = *(const float4*)(cb + (ni * 16 + l15) * 64 + mi * 16 + quad * 4);
        st[mi][ni][0] += cv.x;
        st[mi][ni][1] += cv.y;
        st[mi][ni][2] += cv.z;
        st[mi][ni][3] += cv.w;
      }

    // softmax over keys: 16 lane-local + cross-quad shfl
    float rinv[4];
#pragma unroll
    for (int ni = 0; ni < 4; ++ni) {
      float mx = st[0][ni][0];
#pragma unroll
      for (int mi = 0; mi < 4; ++mi)
#pragma unroll
        for (int r = 0; r < 4; ++r) mx = fmaxf(mx, st[mi][ni][r]);
      mx = fmaxf(mx, __shfl_xor(mx, 16));
      mx = fmaxf(mx, __shfl_xor(mx, 32));
      float sum = 0.f;
#pragma unroll
      for (int mi = 0; mi < 4; ++mi)
#pragma unroll
        for (int r = 0; r < 4; ++r) {
          const float e = __expf(st[mi][ni][r] - mx);
          st[mi][ni][r] = e;
          sum += e;
        }
      sum += __shfl_xor(sum, 16);
      sum += __shfl_xor(sum, 32);
      rinv[ni] = 1.0f / sum;
    }

    // pack P^T to bf16 pairs: pk[mi][ni][t] = keys (mi*16+quad*4+2t, +1), query (ni,l15)
    u32 pk[4][4][2];
#pragma unroll
    for (int mi = 0; mi < 4; ++mi)
#pragma unroll
      for (int ni = 0; ni < 4; ++ni)
#pragma unroll
        for (int t = 0; t < 2; ++t)
          pk[mi][ni][t] = pk2bf(st[mi][ni][2 * t] * rinv[ni],
                                st[mi][ni][2 * t + 1] * rinv[ni]);

    // O^T = V^T P^T : M=32 dims (mb), N=64 queries (nb), K=64 keys (kk)
    floatx4 ot[2][4];
#pragma unroll
    for (int mb = 0; mb < 2; ++mb)
#pragma unroll
      for (int nb = 0; nb < 4; ++nb) ot[mb][nb] = z4;

    const int srcLo = ((quad & 1) * 2) * 16 + l15;
    const int srcHi = srcLo + 16;
    const bool hiSel = (quad >> 1) != 0;
#pragma unroll
    for (int kk = 0; kk < 2; ++kk) {
      short8 av[2];
#pragma unroll
      for (int mb = 0; mb < 2; ++mb)
        av[mb] = *(const short8*)(Vt + (mb * 16 + l15) * 72 + kk * 32 + quad * 8);
#pragma unroll
      for (int nb = 0; nb < 4; ++nb) {
        const int ma = kk * 2, mbx = kk * 2 + 1;
        const u32 a0 = __shfl(pk[ma][nb][0], srcLo), b0 = __shfl(pk[mbx][nb][0], srcLo);
        const u32 a1 = __shfl(pk[ma][nb][1], srcLo), b1 = __shfl(pk[mbx][nb][1], srcLo);
        const u32 a2 = __shfl(pk[ma][nb][0], srcHi), b2 = __shfl(pk[mbx][nb][0], srcHi);
        const u32 a3 = __shfl(pk[ma][nb][1], srcHi), b3 = __shfl(pk[mbx][nb][1], srcHi);
        u32x4 tv = {hiSel ? b0 : a0, hiSel ? b1 : a1, hiSel ? b2 : a2, hiSel ? b3 : a3};
        const short8 pbv = __builtin_bit_cast(short8, tv);
        __builtin_amdgcn_s_setprio(1);
#pragma unroll
        for (int mb = 0; mb < 2; ++mb) ot[mb][nb] = mfma16(av[mb], pbv, ot[mb][nb]);
        __builtin_amdgcn_s_setprio(0);
      }
    }

    // O^T: row=dim=mb*16+quad*4+r, col=query=nb*16+l15 -> aoS[query][h*32+dim]
#pragma unroll
    for (int mb = 0; mb < 2; ++mb)
#pragma unroll
      for (int nb = 0; nb < 4; ++nb) {
        uint2 uv;
        uv.x = pk2bf(ot[mb][nb][0], ot[mb][nb][1]);
        uv.y = pk2bf(ot[mb][nb][2], ot[mb][nb][3]);
        *(uint2*)(aoS + (nb * 16 + l15) * 392 + h * 32 + mb * 16 + quad * 4) = uv;
      }
  }
#undef LOADH

  __syncthreads();  // aoS complete across all waves

  // ---- proj GEMM: (64x384 from aoS) @ (384x384 pw)^T, wave wv owns cols wv*96..+96 ----
  floatx4 pacc[4][6];
#pragma unroll
  for (int mi = 0; mi < 4; ++mi)
#pragma unroll
    for (int nf = 0; nf < 6; ++nf) pacc[mi][nf] = z4;

  const u16* pwb = pw + (size_t)(wv * 96 + l15) * 384 + quad * 8;
#pragma unroll
  for (int kb = 0; kb < 12; ++kb) {
    short8 paf[4], pbf[6];
#pragma unroll
    for (int mi = 0; mi < 4; ++mi)
      paf[mi] = *(const short8*)(aoS + (mi * 16 + l15) * 392 + kb * 32 + quad * 8);
#pragma unroll
    for (int nf = 0; nf < 6; ++nf)
      pbf[nf] = *(const short8*)(pwb + nf * 6144 + kb * 32);
    __builtin_amdgcn_s_setprio(1);
#pragma unroll
    for (int mi = 0; mi < 4; ++mi)
#pragma unroll
      for (int nf = 0; nf < 6; ++nf)
        pacc[mi][nf] = mfma16(paf[mi], pbf[nf], pacc[mi][nf]);
    __builtin_amdgcn_s_setprio(0);
  }

#pragma unroll
  for (int nf = 0; nf < 6; ++nf) {
    const int col = wv * 96 + nf * 16 + l15;
    const float bb = pb[col];
#pragma unroll
    for (int mi = 0; mi < 4; ++mi)
#pragma unroll
      for (int r = 0; r < 4; ++r) {
        const int row = mi * 16 + quad * 4 + r;
        if (row < 49)
          out[((size_t)b * 49 + row) * 384 + col] = pacc[mi][nf][r] + bb;
      }
  }
}

// ---------------- launcher ----------------
extern "C" void kernel_launch(void* const* d_in, const int* in_sizes, int n_in,
                              void* d_out, int out_size, void* d_ws, size_t ws_size,
                              hipStream_t stream) {
  const float* x = (const float*)d_in[0];
  const float* mask = (const float*)d_in[1];
  const float* qkv_w = (const float*)d_in[2];
  const float* qkv_b = (const float*)d_in[3];
  const float* proj_w = (const float*)d_in[4];
  const float* proj_b = (const float*)d_in[5];
  const float* bias_table = (const float*)d_in[6];
  float* out = (float*)d_out;
  char* ws = (char*)d_ws;

  u16* wb1 = (u16*)(ws);                        // 442368 bf16 = 884736 B
  u16* wb2 = (u16*)(ws + 884736);               // 147456 bf16 = 294912 B
  float* comb = (float*)(ws + 1179648);         // 768*4096 f32 = 12582912 B
  u16* qkvb = (u16*)(ws + 13762560);            // 200704*1152 bf16 = 462422016 B (head-major)
  // x is cast in-kernel; total ws use: 476184576 B

  hipLaunchKernelGGL(cast_w_kernel, dim3(1728), dim3(256), 0, stream, qkv_w, proj_w, wb1, wb2);
  hipLaunchKernelGGL(comb_kernel, dim3(768), dim3(256), 0, stream, bias_table, mask, comb);
  hipLaunchKernelGGL(qkv_gemm, dim3(14112), dim3(256), 0, stream, x, wb1, qkv_b, qkvb);
  hipLaunchKernelGGL(attn_proj, dim3(4096), dim3(256), 0, stream, qkvb, comb, wb2, proj_b, out);
}